// Round 1
// baseline (17.309 us; speedup 1.0000x reference)
//
#include <hip/hip_runtime.h>
#include <math.h>

// Problem geometry (fixed by setup_inputs): 256 x 8192 x 3 f32, two inputs.
#define N_ROWS   (256 * 8192)         // 2,097,152 rows of 3 floats
#define ROWS_PER_THREAD 4
#define N_THREADS (N_ROWS / ROWS_PER_THREAD)  // 524,288
#define BLOCK 256
#define GRID  (N_THREADS / BLOCK)     // 2048 blocks, exact

__global__ __launch_bounds__(BLOCK) void angle_partial(
    const float* __restrict__ o,
    const float* __restrict__ t,
    float* __restrict__ partial)
{
    const int tid = blockIdx.x * BLOCK + threadIdx.x;

    // Each thread: 3 float4 = 12 contiguous floats = 4 rows of 3.
    const float4* o4 = reinterpret_cast<const float4*>(o);
    const float4* t4 = reinterpret_cast<const float4*>(t);
    const long base = (long)tid * 3;

    float4 a0 = o4[base + 0];
    float4 a1 = o4[base + 1];
    float4 a2 = o4[base + 2];
    float4 b0 = t4[base + 0];
    float4 b1 = t4[base + 1];
    float4 b2 = t4[base + 2];

    // Unpack 12 floats -> 4 rows (x,y,z)
    float ox[4] = {a0.x, a0.w, a1.z, a2.y};
    float oy[4] = {a0.y, a1.x, a1.w, a2.z};
    float oz[4] = {a0.z, a1.y, a2.x, a2.w};
    float tx[4] = {b0.x, b0.w, b1.z, b2.y};
    float ty[4] = {b0.y, b1.x, b1.w, b2.z};
    float tz[4] = {b0.z, b1.y, b2.x, b2.w};

    float s = 0.0f;
#pragma unroll
    for (int r = 0; r < 4; ++r) {
        float dot = ox[r] * tx[r] + oy[r] * ty[r] + oz[r] * tz[r];
        float no2 = ox[r] * ox[r] + oy[r] * oy[r] + oz[r] * oz[r];
        float nt2 = tx[r] * tx[r] + ty[r] * ty[r] + tz[r] * tz[r];
        float c = dot * rsqrtf(no2) * rsqrtf(nt2);
        c = fminf(1.0f, fmaxf(-1.0f, c));
        s += acosf(c);
    }

    // Wave (64-lane) reduction
#pragma unroll
    for (int off = 32; off > 0; off >>= 1)
        s += __shfl_down(s, off, 64);

    __shared__ float waves[BLOCK / 64];
    const int lane = threadIdx.x & 63;
    const int wid  = threadIdx.x >> 6;
    if (lane == 0) waves[wid] = s;
    __syncthreads();

    if (threadIdx.x == 0) {
        float bs = 0.0f;
#pragma unroll
        for (int w = 0; w < BLOCK / 64; ++w) bs += waves[w];
        partial[blockIdx.x] = bs;
    }
}

__global__ __launch_bounds__(BLOCK) void angle_final(
    const float* __restrict__ partial,
    float* __restrict__ out)
{
    // Deterministic: fixed-order per-thread strided sums, then shuffle+LDS.
    float s = 0.0f;
    for (int i = threadIdx.x; i < GRID; i += BLOCK)
        s += partial[i];

#pragma unroll
    for (int off = 32; off > 0; off >>= 1)
        s += __shfl_down(s, off, 64);

    __shared__ float waves[BLOCK / 64];
    const int lane = threadIdx.x & 63;
    const int wid  = threadIdx.x >> 6;
    if (lane == 0) waves[wid] = s;
    __syncthreads();

    if (threadIdx.x == 0) {
        float total = 0.0f;
#pragma unroll
        for (int w = 0; w < BLOCK / 64; ++w) total += waves[w];
        out[0] = total / (float)N_ROWS;
    }
}

extern "C" void kernel_launch(void* const* d_in, const int* in_sizes, int n_in,
                              void* d_out, int out_size, void* d_ws, size_t ws_size,
                              hipStream_t stream)
{
    const float* outputs = (const float*)d_in[0];
    const float* targets = (const float*)d_in[1];
    float* out = (float*)d_out;
    float* partial = (float*)d_ws;  // GRID floats = 8 KB scratch

    angle_partial<<<GRID, BLOCK, 0, stream>>>(outputs, targets, partial);
    angle_final<<<1, BLOCK, 0, stream>>>(partial, out);
}